// Round 9
// baseline (413.343 us; speedup 1.0000x reference)
//
#include <hip/hip_runtime.h>

typedef unsigned short ushort_t;
using f32x4  = __attribute__((ext_vector_type(4))) float;
using bf16x8 = __attribute__((ext_vector_type(8))) short;
using u16x8  = __attribute__((ext_vector_type(8))) unsigned short;
using h2v    = __attribute__((ext_vector_type(2))) _Float16;

constexpr int Bc = 4;
constexpr int Nc = 512;
constexpr int Dc = 512;
constexpr int Pc = 128;
constexpr int ROWS = Bc * Nc;   // 2048

// ---- measurement round: in-kernel repetition factors (idempotent reps) ----
constexpr int WREP = 64;   // wconv   ~1.2us -> ~77us  (visible over 40us fills)
constexpr int PREP = 24;   // proj    ~3.5us -> ~84us
constexpr int BREP = 24;   // bigram  ~5us   -> ~120us

__device__ inline unsigned short f2bf(float f) {
    unsigned u = __builtin_bit_cast(unsigned, f);
    unsigned r = u + 0x7fffu + ((u >> 16) & 1u);   // RNE
    return (unsigned short)(r >> 16);
}

__device__ inline void gload_lds16(const void* g, void* l) {
    __builtin_amdgcn_global_load_lds(
        (const __attribute__((address_space(1))) unsigned int*)g,
        (__attribute__((address_space(3))) unsigned int*)l, 16, 0, 0);
}

__device__ inline unsigned packh2(float a, float b) {
    unsigned short lo = __builtin_bit_cast(unsigned short, (_Float16)a);
    unsigned short hi = __builtin_bit_cast(unsigned short, (_Float16)b);
    return (unsigned)lo | ((unsigned)hi << 16);
}

// ---------------------------------------------------------------------------
// K0: W-only convert -> WcatT2[nt(8)][ks(8)][kc(8)][col(64)][8] bf16.
// ---------------------------------------------------------------------------
__global__ __launch_bounds__(256) void wconv_kernel(
    const float* __restrict__ Wl,  const float* __restrict__ Wr,
    const float* __restrict__ Ws1, const float* __restrict__ We1,
    ushort_t* __restrict__ WcatT2)
{
    const int bx = blockIdx.x, t = threadIdx.x;
    __shared__ float T[64][68];

    const int nt = bx >> 3, ks = bx & 7;
    const int mi = nt >> 1, cm0 = (nt & 1) * 64;
    const float* Wm = (mi == 0) ? Wl : (mi == 1) ? Wr : (mi == 2) ? Ws1 : We1;

    const int kk_ = t >> 4, cc = (t & 15) << 2;
    const int col = t & 63, c2 = t >> 6;

    for (int rep = 0; rep < WREP; ++rep) {
        asm volatile("" ::: "memory");
        __syncthreads();
        #pragma unroll
        for (int u = 0; u < 4; ++u)
            *(float4*)&T[kk_ + 16 * u][cc] =
                *(const float4*)&Wm[(size_t)(ks * 64 + kk_ + 16 * u) * Pc + cm0 + cc];
        __syncthreads();
        #pragma unroll
        for (int h = 0; h < 2; ++h) {
            const int kc = c2 + h * 4;
            u16x8 o;
            #pragma unroll
            for (int i = 0; i < 8; ++i) o[i] = f2bf(T[kc * 8 + i][col]);
            *(u16x8*)(WcatT2 + ((size_t)(nt * 8 + ks) * 8 + kc) * 512 + col * 8) = o;
        }
    }
}

// ---------------------------------------------------------------------------
// K1: proj GEMM with fused input conversion (round-8 structure, REP-looped).
// ---------------------------------------------------------------------------
__global__ __launch_bounds__(256) void mfma_proj4(
    const float* __restrict__ input, const ushort_t* __restrict__ WcatT2,
    const float* __restrict__ bl,
    const float* __restrict__ bs1, const float* __restrict__ Ws2,
    const float* __restrict__ be1, const float* __restrict__ We2,
    ushort_t* __restrict__ leftH, ushort_t* __restrict__ rightH,
    float* __restrict__ parts)
{
    const int mt2 = blockIdx.x, ny = blockIdx.y;
    const int row0 = mt2 * 32;
    const int t = threadIdx.x, w = t >> 6, l = t & 63;
    const int wm = w & 1, wn = w >> 1;
    const int fr = l & 15, fg = l >> 4;

    __shared__ ushort_t As[2][2048];
    __shared__ ushort_t Bs[2][4096];
    __shared__ float red[64];

    const ushort_t* Bbase = WcatT2 + (size_t)ny * 8 * 4096;

    const int sr = t >> 3, skc = t & 7;
    const float* Ain = input + (size_t)(row0 + sr) * Dc + skc * 8;
    ushort_t* Ad0 = &As[0][skc * 256 + sr * 8];
    ushort_t* Ad1 = &As[1][skc * 256 + sr * 8];

#define ALOAD(P0, P1, KS)                                     \
    {                                                         \
        const float* s_ = Ain + (KS) * 64;                    \
        P0 = *(const float4*)s_;                              \
        P1 = *(const float4*)(s_ + 4);                        \
    }

#define AWRITE(DST, P0, P1)                                   \
    {                                                         \
        u16x8 o_;                                             \
        o_[0] = f2bf(P0.x); o_[1] = f2bf(P0.y);               \
        o_[2] = f2bf(P0.z); o_[3] = f2bf(P0.w);               \
        o_[4] = f2bf(P1.x); o_[5] = f2bf(P1.y);               \
        o_[6] = f2bf(P1.z); o_[7] = f2bf(P1.w);               \
        *(u16x8*)(DST) = o_;                                  \
    }

#define BSTAGE(BI, KS)                                                   \
    {                                                                    \
        const ushort_t* gb = Bbase + (KS) * 4096;                        \
        gload_lds16(gb + w * 512 + l * 8, &Bs[BI][w * 512]);             \
        gload_lds16(gb + (w + 4) * 512 + l * 8, &Bs[BI][(w + 4) * 512]); \
    }

#define COMPUTE(BI)                                                           \
    {                                                                         \
        _Pragma("unroll") for (int kk = 0; kk < 2; ++kk) {                    \
            const int kc = kk * 4 + fg;                                       \
            bf16x8 a  = *(const bf16x8*)&As[BI][kc * 256 + (wm * 16 + fr) * 8];       \
            bf16x8 b0 = *(const bf16x8*)&Bs[BI][kc * 512 + (wn * 32 + fr) * 8];       \
            bf16x8 b1 = *(const bf16x8*)&Bs[BI][kc * 512 + (wn * 32 + 16 + fr) * 8];  \
            acc0 = __builtin_amdgcn_mfma_f32_16x16x32_bf16(a, b0, acc0, 0, 0, 0);     \
            acc1 = __builtin_amdgcn_mfma_f32_16x16x32_bf16(a, b1, acc1, 0, 0, 0);     \
        }                                                                     \
    }

    for (int rep = 0; rep < PREP; ++rep) {
        asm volatile("" ::: "memory");
        __syncthreads();

        f32x4 acc0 = {0.f, 0.f, 0.f, 0.f}, acc1 = {0.f, 0.f, 0.f, 0.f};
        float4 aE0, aE1, aO0, aO1;

        ALOAD(aE0, aE1, 0);
        BSTAGE(0, 0);
        AWRITE(Ad0, aE0, aE1);
        ALOAD(aO0, aO1, 1);
        __syncthreads();

        #pragma unroll
        for (int ks2 = 0; ks2 < 8; ks2 += 2) {
            BSTAGE(1, ks2 + 1);
            if (ks2 + 2 < 8) ALOAD(aE0, aE1, ks2 + 2);
            COMPUTE(0);
            AWRITE(Ad1, aO0, aO1);
            __syncthreads();
            if (ks2 + 2 < 8) {
                BSTAGE(0, ks2 + 2);
                if (ks2 + 3 < 8) ALOAD(aO0, aO1, ks2 + 3);
            }
            COMPUTE(1);
            if (ks2 + 2 < 8) AWRITE(Ad0, aE0, aE1);
            __syncthreads();
        }

        const int fq4 = fg << 2;
        if (ny < 4) {
            ushort_t* outp = (ny < 2) ? leftH : rightH;
            const int cb = (ny & 1) * 64 + wn * 32;
            #pragma unroll
            for (int n = 0; n < 2; ++n) {
                const int col = cb + n * 16 + fr;
                const float bv = (ny < 2) ? bl[col] : 0.f;
                const f32x4 av = n ? acc1 : acc0;
                #pragma unroll
                for (int q = 0; q < 4; ++q) {
                    float v = av[q] + bv;
                    outp[(size_t)(row0 + wm * 16 + fq4 + q) * Pc + col] =
                        __builtin_bit_cast(ushort_t, (_Float16)v);
                }
            }
        } else {
            const int pi = ny - 4;
            const float* b1 = (ny < 6) ? bs1 : be1;
            const float* W2 = (ny < 6) ? Ws2 : We2;
            const int pb = (pi & 1) * 64;
            #pragma unroll
            for (int q = 0; q < 4; ++q) {
                const int cp0 = pb + wn * 32 + fr;
                const int cp1 = pb + wn * 32 + 16 + fr;
                float v = fmaxf(acc0[q] + b1[cp0], 0.f) * W2[cp0]
                        + fmaxf(acc1[q] + b1[cp1], 0.f) * W2[cp1];
                v += __shfl_xor(v, 1);
                v += __shfl_xor(v, 2);
                v += __shfl_xor(v, 4);
                v += __shfl_xor(v, 8);
                if (fr == 0) red[wn * 32 + wm * 16 + fq4 + q] = v;
            }
            __syncthreads();
            if (t < 32) parts[pi * ROWS + row0 + t] = red[t] + red[32 + t];
        }
    }
#undef ALOAD
#undef AWRITE
#undef BSTAGE
#undef COMPUTE
}

// ---------------------------------------------------------------------------
// K2: bigram v4 (round-8 structure, REP-looped).
// ---------------------------------------------------------------------------
__global__ __launch_bounds__(256) void bigram_kernel(
    const ushort_t* __restrict__ leftH, const ushort_t* __restrict__ rightH,
    const float* __restrict__ Wo,   const float* __restrict__ bo,
    const float* __restrict__ parts,
    const float* __restrict__ bs2,  const float* __restrict__ be2,
    float* __restrict__ out, float* __restrict__ start_out,
    float* __restrict__ end_out)
{
    const int jt = blockIdx.x, it = blockIdx.y, b = blockIdx.z;
    const int t  = threadIdx.x;

    if (jt == 16) {
        const int base = (b * 8 + it) * 64;
        if (t < 64) {
            const int r = base + t;
            start_out[r] = parts[r] + parts[ROWS + r] + bs2[0];
        } else if (t < 128) {
            const int r = base + t - 64;
            end_out[r] = parts[2 * ROWS + r] + parts[3 * ROWS + r] + be2[0];
        }
        return;
    }

    __shared__ unsigned Lh[32][68];
    __shared__ unsigned Rh[64][68];
    __shared__ unsigned woh[64];

    const ushort_t* lp = leftH  + (size_t)(b * Nc + jt * 32) * Pc;
    const ushort_t* rp = rightH + (size_t)(b * Nc + it * 64) * Pc;

    const int jl = t & 15;
    const int il = t >> 4;
    const h2v hz = {(_Float16)0.f, (_Float16)0.f};

#define DOTH(COMP)                                                       \
    {                                                                    \
        const unsigned wu = w4.COMP;                                     \
        h2v lv[2], rv[4];                                                \
        lv[0] = __builtin_bit_cast(h2v, l4[0].COMP);                     \
        lv[1] = __builtin_bit_cast(h2v, l4[1].COMP);                     \
        rv[0] = __builtin_bit_cast(h2v, r4[0].COMP);                     \
        rv[1] = __builtin_bit_cast(h2v, r4[1].COMP);                     \
        rv[2] = __builtin_bit_cast(h2v, r4[2].COMP);                     \
        rv[3] = __builtin_bit_cast(h2v, r4[3].COMP);                     \
        _Pragma("unroll") for (int ii = 0; ii < 4; ++ii)                 \
        _Pragma("unroll") for (int jj = 0; jj < 2; ++jj) {               \
            h2v sum = lv[jj] + rv[ii];                                   \
            sum = __builtin_elementwise_max(sum, hz);                    \
            unsigned su = __builtin_bit_cast(unsigned, sum);             \
            asm("v_dot2_f32_f16 %0, %1, %2, %0"                          \
                : "+v"(acc[ii][jj]) : "v"(su), "v"(wu));                 \
        }                                                                \
    }

    for (int rep = 0; rep < BREP; ++rep) {
        asm volatile("" ::: "memory");
        __syncthreads();

        #pragma unroll
        for (int u = 0; u < 2; ++u) {
            int f = t + u * 256, r = f >> 4, c = f & 15;
            *(float4*)&Lh[r][c * 4] = *(const float4*)(lp + (size_t)r * Pc + c * 8);
        }
        #pragma unroll
        for (int u = 0; u < 4; ++u) {
            int f = t + u * 256, r = f >> 4, c = f & 15;
            *(float4*)&Rh[r][c * 4] = *(const float4*)(rp + (size_t)r * Pc + c * 8);
        }
        if (t < 64) woh[t] = packh2(Wo[2 * t], Wo[2 * t + 1]);
        __syncthreads();

        float acc[4][2] = {};

        #pragma unroll 4
        for (int s4 = 0; s4 < 16; ++s4) {
            uint4 w4 = *(const uint4*)&woh[4 * s4];
            uint4 l4[2], r4[4];
            #pragma unroll
            for (int jj = 0; jj < 2; ++jj) l4[jj] = *(const uint4*)&Lh[jl + 16 * jj][4 * s4];
            #pragma unroll
            for (int ii = 0; ii < 4; ++ii) r4[ii] = *(const uint4*)&Rh[il + 16 * ii][4 * s4];
            DOTH(x) DOTH(y) DOTH(z) DOTH(w)
        }

        const float bias = bo[0];
        #pragma unroll
        for (int ii = 0; ii < 4; ++ii) {
            #pragma unroll
            for (int jj = 0; jj < 2; ++jj) {
                const int gi = it * 64 + il + 16 * ii;
                const int gj = jt * 32 + jl + 16 * jj;
                out[((size_t)b * Nc + gi) * Nc + gj] = acc[ii][jj] + bias;
            }
        }
    }
#undef DOTH
}

extern "C" void kernel_launch(void* const* d_in, const int* in_sizes, int n_in,
                              void* d_out, int out_size, void* d_ws, size_t ws_size,
                              hipStream_t stream) {
    const float* input = (const float*)d_in[0];
    const float* Wl  = (const float*)d_in[1];
    const float* bl  = (const float*)d_in[2];
    const float* Wr  = (const float*)d_in[3];
    const float* Wo  = (const float*)d_in[4];
    const float* bo  = (const float*)d_in[5];
    const float* Ws1 = (const float*)d_in[6];
    const float* bs1 = (const float*)d_in[7];
    const float* Ws2 = (const float*)d_in[8];
    const float* bs2 = (const float*)d_in[9];
    const float* We1 = (const float*)d_in[10];
    const float* be1 = (const float*)d_in[11];
    const float* We2 = (const float*)d_in[12];
    const float* be2 = (const float*)d_in[13];

    float* out    = (float*)d_out;
    float* bigram = out;
    float* start  = out + (size_t)Bc * Nc * Nc;
    float* end    = start + (size_t)Bc * Nc;

    ushort_t* leftH  = (ushort_t*)d_ws;                        // 2048*128 f16
    ushort_t* rightH = leftH + (size_t)ROWS * Pc;              // 2048*128 f16
    float* parts     = (float*)(rightH + (size_t)ROWS * Pc);   // 4*2048 f32
    ushort_t* WcatT2 = (ushort_t*)(parts + 4 * ROWS);          // 512*512 bf16

    wconv_kernel<<<64, 256, 0, stream>>>(Wl, Wr, Ws1, We1, WcatT2);

    mfma_proj4<<<dim3(64, 8), 256, 0, stream>>>(
        input, WcatT2, bl, bs1, Ws2, be1, We2, leftH, rightH, parts);

    bigram_kernel<<<dim3(17, 8, 4), 256, 0, stream>>>(
        leftH, rightH, Wo, bo, parts, bs2, be2, bigram, start, end);
}

// Round 10
// 36.289 us; speedup vs baseline: 11.3904x; 11.3904x over previous
//
#include <hip/hip_runtime.h>

typedef unsigned short ushort_t;
using f32x4  = __attribute__((ext_vector_type(4))) float;
using bf16x8 = __attribute__((ext_vector_type(8))) short;
using u16x8  = __attribute__((ext_vector_type(8))) unsigned short;
using h2v    = __attribute__((ext_vector_type(2))) _Float16;

constexpr int Bc = 4;
constexpr int Nc = 512;
constexpr int Dc = 512;
constexpr int Pc = 128;
constexpr int ROWS = Bc * Nc;   // 2048

__device__ inline unsigned short f2bf(float f) {
    unsigned u = __builtin_bit_cast(unsigned, f);
    unsigned r = u + 0x7fffu + ((u >> 16) & 1u);   // RNE
    return (unsigned short)(r >> 16);
}

__device__ inline void gload_lds16(const void* g, void* l) {
    __builtin_amdgcn_global_load_lds(
        (const __attribute__((address_space(1))) unsigned int*)g,
        (__attribute__((address_space(3))) unsigned int*)l, 16, 0, 0);
}

__device__ inline unsigned packh2(float a, float b) {
    unsigned short lo = __builtin_bit_cast(unsigned short, (_Float16)a);
    unsigned short hi = __builtin_bit_cast(unsigned short, (_Float16)b);
    return (unsigned)lo | ((unsigned)hi << 16);
}

// ---------------------------------------------------------------------------
// K0: W-only convert -> WcatT2[nt(8)][ks(8)][kc(8)][col(64)][8] bf16.
// ---------------------------------------------------------------------------
__global__ __launch_bounds__(256) void wconv_kernel(
    const float* __restrict__ Wl,  const float* __restrict__ Wr,
    const float* __restrict__ Ws1, const float* __restrict__ We1,
    ushort_t* __restrict__ WcatT2)
{
    const int bx = blockIdx.x, t = threadIdx.x;
    __shared__ float T[64][68];

    const int nt = bx >> 3, ks = bx & 7;
    const int mi = nt >> 1, cm0 = (nt & 1) * 64;
    const float* Wm = (mi == 0) ? Wl : (mi == 1) ? Wr : (mi == 2) ? Ws1 : We1;

    const int kk_ = t >> 4, cc = (t & 15) << 2;
    #pragma unroll
    for (int u = 0; u < 4; ++u)
        *(float4*)&T[kk_ + 16 * u][cc] =
            *(const float4*)&Wm[(size_t)(ks * 64 + kk_ + 16 * u) * Pc + cm0 + cc];
    __syncthreads();

    const int col = t & 63, c2 = t >> 6;
    #pragma unroll
    for (int h = 0; h < 2; ++h) {
        const int kc = c2 + h * 4;
        u16x8 o;
        #pragma unroll
        for (int i = 0; i < 8; ++i) o[i] = f2bf(T[kc * 8 + i][col]);
        *(u16x8*)(WcatT2 + ((size_t)(nt * 8 + ks) * 8 + kc) * 512 + col * 8) = o;
    }
}

// ---------------------------------------------------------------------------
// K1: proj GEMM with fused input conversion (round-8 structure, unchanged).
// ---------------------------------------------------------------------------
__global__ __launch_bounds__(256) void mfma_proj4(
    const float* __restrict__ input, const ushort_t* __restrict__ WcatT2,
    const float* __restrict__ bl,
    const float* __restrict__ bs1, const float* __restrict__ Ws2,
    const float* __restrict__ be1, const float* __restrict__ We2,
    ushort_t* __restrict__ leftH, ushort_t* __restrict__ rightH,
    float* __restrict__ parts)
{
    const int mt2 = blockIdx.x, ny = blockIdx.y;
    const int row0 = mt2 * 32;
    const int t = threadIdx.x, w = t >> 6, l = t & 63;
    const int wm = w & 1, wn = w >> 1;
    const int fr = l & 15, fg = l >> 4;

    __shared__ ushort_t As[2][2048];
    __shared__ ushort_t Bs[2][4096];
    __shared__ float red[64];

    const ushort_t* Bbase = WcatT2 + (size_t)ny * 8 * 4096;

    const int sr = t >> 3, skc = t & 7;
    const float* Ain = input + (size_t)(row0 + sr) * Dc + skc * 8;
    ushort_t* Ad0 = &As[0][skc * 256 + sr * 8];
    ushort_t* Ad1 = &As[1][skc * 256 + sr * 8];

    f32x4 acc0 = {0.f, 0.f, 0.f, 0.f}, acc1 = {0.f, 0.f, 0.f, 0.f};
    float4 aE0, aE1, aO0, aO1;

#define ALOAD(P0, P1, KS)                                     \
    {                                                         \
        const float* s_ = Ain + (KS) * 64;                    \
        P0 = *(const float4*)s_;                              \
        P1 = *(const float4*)(s_ + 4);                        \
    }

#define AWRITE(DST, P0, P1)                                   \
    {                                                         \
        u16x8 o_;                                             \
        o_[0] = f2bf(P0.x); o_[1] = f2bf(P0.y);               \
        o_[2] = f2bf(P0.z); o_[3] = f2bf(P0.w);               \
        o_[4] = f2bf(P1.x); o_[5] = f2bf(P1.y);               \
        o_[6] = f2bf(P1.z); o_[7] = f2bf(P1.w);               \
        *(u16x8*)(DST) = o_;                                  \
    }

#define BSTAGE(BI, KS)                                                   \
    {                                                                    \
        const ushort_t* gb = Bbase + (KS) * 4096;                        \
        gload_lds16(gb + w * 512 + l * 8, &Bs[BI][w * 512]);             \
        gload_lds16(gb + (w + 4) * 512 + l * 8, &Bs[BI][(w + 4) * 512]); \
    }

#define COMPUTE(BI)                                                           \
    {                                                                         \
        _Pragma("unroll") for (int kk = 0; kk < 2; ++kk) {                    \
            const int kc = kk * 4 + fg;                                       \
            bf16x8 a  = *(const bf16x8*)&As[BI][kc * 256 + (wm * 16 + fr) * 8];       \
            bf16x8 b0 = *(const bf16x8*)&Bs[BI][kc * 512 + (wn * 32 + fr) * 8];       \
            bf16x8 b1 = *(const bf16x8*)&Bs[BI][kc * 512 + (wn * 32 + 16 + fr) * 8];  \
            acc0 = __builtin_amdgcn_mfma_f32_16x16x32_bf16(a, b0, acc0, 0, 0, 0);     \
            acc1 = __builtin_amdgcn_mfma_f32_16x16x32_bf16(a, b1, acc1, 0, 0, 0);     \
        }                                                                     \
    }

    ALOAD(aE0, aE1, 0);
    BSTAGE(0, 0);
    AWRITE(Ad0, aE0, aE1);
    ALOAD(aO0, aO1, 1);
    __syncthreads();

    #pragma unroll
    for (int ks2 = 0; ks2 < 8; ks2 += 2) {
        BSTAGE(1, ks2 + 1);
        if (ks2 + 2 < 8) ALOAD(aE0, aE1, ks2 + 2);
        COMPUTE(0);
        AWRITE(Ad1, aO0, aO1);
        __syncthreads();
        if (ks2 + 2 < 8) {
            BSTAGE(0, ks2 + 2);
            if (ks2 + 3 < 8) ALOAD(aO0, aO1, ks2 + 3);
        }
        COMPUTE(1);
        if (ks2 + 2 < 8) AWRITE(Ad0, aE0, aE1);
        __syncthreads();
    }
#undef ALOAD
#undef AWRITE
#undef BSTAGE
#undef COMPUTE

    const int fq4 = fg << 2;
    if (ny < 4) {
        ushort_t* outp = (ny < 2) ? leftH : rightH;
        const int cb = (ny & 1) * 64 + wn * 32;
        #pragma unroll
        for (int n = 0; n < 2; ++n) {
            const int col = cb + n * 16 + fr;
            const float bv = (ny < 2) ? bl[col] : 0.f;
            const f32x4 av = n ? acc1 : acc0;
            #pragma unroll
            for (int q = 0; q < 4; ++q) {
                float v = av[q] + bv;
                outp[(size_t)(row0 + wm * 16 + fq4 + q) * Pc + col] =
                    __builtin_bit_cast(ushort_t, (_Float16)v);
            }
        }
    } else {
        const int pi = ny - 4;
        const float* b1 = (ny < 6) ? bs1 : be1;
        const float* W2 = (ny < 6) ? Ws2 : We2;
        const int pb = (pi & 1) * 64;
        #pragma unroll
        for (int q = 0; q < 4; ++q) {
            const int cp0 = pb + wn * 32 + fr;
            const int cp1 = pb + wn * 32 + 16 + fr;
            float v = fmaxf(acc0[q] + b1[cp0], 0.f) * W2[cp0]
                    + fmaxf(acc1[q] + b1[cp1], 0.f) * W2[cp1];
            v += __shfl_xor(v, 1);
            v += __shfl_xor(v, 2);
            v += __shfl_xor(v, 4);
            v += __shfl_xor(v, 8);
            if (fr == 0) red[wn * 32 + wm * 16 + fq4 + q] = v;
        }
        __syncthreads();
        if (t < 32) parts[pi * ROWS + row0 + t] = red[t] + red[32 + t];
    }
}

// ---------------------------------------------------------------------------
// K2: bigram v5. Tile 64i x 64j, thread = 4i x 4j (16 outputs), 256 blocks.
// fdot2 builtins (no asm pinning) + 2-deep ping-pong LDS prefetch; no
// barriers in the p-loop. grid (9,8,4): jt==8 combines start/end partials.
// ---------------------------------------------------------------------------
__global__ __launch_bounds__(256) void bigram_kernel(
    const ushort_t* __restrict__ leftH, const ushort_t* __restrict__ rightH,
    const float* __restrict__ Wo,   const float* __restrict__ bo,
    const float* __restrict__ parts,
    const float* __restrict__ bs2,  const float* __restrict__ be2,
    float* __restrict__ out, float* __restrict__ start_out,
    float* __restrict__ end_out)
{
    const int jt = blockIdx.x, it = blockIdx.y, b = blockIdx.z;
    const int t  = threadIdx.x;

    if (jt == 8) {
        const int base = (b * 8 + it) * 64;
        if (t < 64) {
            const int r = base + t;
            start_out[r] = parts[r] + parts[ROWS + r] + bs2[0];
        } else if (t < 128) {
            const int r = base + t - 64;
            end_out[r] = parts[2 * ROWS + r] + parts[3 * ROWS + r] + be2[0];
        }
        return;
    }

    __shared__ unsigned Lh[64][68];   // 64 j-rows, 64 f16-pairs + pad
    __shared__ unsigned Rh[64][68];   // 64 i-rows
    __shared__ unsigned woh[64];

    const ushort_t* lp = leftH  + (size_t)(b * Nc + jt * 64) * Pc;
    const ushort_t* rp = rightH + (size_t)(b * Nc + it * 64) * Pc;

    #pragma unroll
    for (int u = 0; u < 4; ++u) {
        int f = t + u * 256, r = f >> 4, c = f & 15;
        *(float4*)&Lh[r][c * 4] = *(const float4*)(lp + (size_t)r * Pc + c * 8);
    }
    #pragma unroll
    for (int u = 0; u < 4; ++u) {
        int f = t + u * 256, r = f >> 4, c = f & 15;
        *(float4*)&Rh[r][c * 4] = *(const float4*)(rp + (size_t)r * Pc + c * 8);
    }
    if (t < 64) woh[t] = packh2(Wo[2 * t], Wo[2 * t + 1]);
    __syncthreads();

    const int jl = t & 15;   // j = jl + 16*jj, jj<4
    const int il = t >> 4;   // i = il + 16*ii, ii<4

    float acc[4][4] = {};    // [ii][jj]
    const h2v hz = {(_Float16)0.f, (_Float16)0.f};

#define LOADP(S, W4, L4, R4)                                             \
    {                                                                    \
        W4 = *(const uint4*)&woh[4 * (S)];                               \
        _Pragma("unroll") for (int jj = 0; jj < 4; ++jj)                 \
            L4[jj] = *(const uint4*)&Lh[jl + 16 * jj][4 * (S)];          \
        _Pragma("unroll") for (int ii = 0; ii < 4; ++ii)                 \
            R4[ii] = *(const uint4*)&Rh[il + 16 * ii][4 * (S)];          \
    }

#define COMP1(W4, L4, R4, C)                                             \
    {                                                                    \
        const h2v wv = __builtin_bit_cast(h2v, W4.C);                    \
        h2v lv[4] = {__builtin_bit_cast(h2v, L4[0].C),                   \
                     __builtin_bit_cast(h2v, L4[1].C),                   \
                     __builtin_bit_cast(h2v, L4[2].C),                   \
                     __builtin_bit_cast(h2v, L4[3].C)};                  \
        h2v rv[4] = {__builtin_bit_cast(h2v, R4[0].C),                   \
                     __builtin_bit_cast(h2v, R4[1].C),                   \
                     __builtin_bit_cast(h2v, R4[2].C),                   \
                     __builtin_bit_cast(h2v, R4[3].C)};                  \
        _Pragma("unroll") for (int ii = 0; ii < 4; ++ii)                 \
        _Pragma("unroll") for (int jj = 0; jj < 4; ++jj) {               \
            h2v sum = lv[jj] + rv[ii];                                   \
            sum = __builtin_elementwise_max(sum, hz);                    \
            acc[ii][jj] = __builtin_amdgcn_fdot2(sum, wv, acc[ii][jj], false); \
        }                                                                \
    }

#define COMP(W4, L4, R4)                                                 \
    { COMP1(W4, L4, R4, x) COMP1(W4, L4, R4, y)                          \
      COMP1(W4, L4, R4, z) COMP1(W4, L4, R4, w) }

    uint4 wA, lA[4], rA[4];
    uint4 wB, lB[4], rB[4];
    LOADP(0, wA, lA, rA);

    #pragma unroll 1
    for (int s = 0; s < 16; s += 2) {
        LOADP(s + 1, wB, lB, rB);
        COMP(wA, lA, rA);
        if (s + 2 < 16) LOADP(s + 2, wA, lA, rA);
        COMP(wB, lB, rB);
    }
#undef LOADP
#undef COMP1
#undef COMP

    const float bias = bo[0];
    #pragma unroll
    for (int ii = 0; ii < 4; ++ii) {
        #pragma unroll
        for (int jj = 0; jj < 4; ++jj) {
            const int gi = it * 64 + il + 16 * ii;
            const int gj = jt * 64 + jl + 16 * jj;
            out[((size_t)b * Nc + gi) * Nc + gj] = acc[ii][jj] + bias;
        }
    }
}

extern "C" void kernel_launch(void* const* d_in, const int* in_sizes, int n_in,
                              void* d_out, int out_size, void* d_ws, size_t ws_size,
                              hipStream_t stream) {
    const float* input = (const float*)d_in[0];
    const float* Wl  = (const float*)d_in[1];
    const float* bl  = (const float*)d_in[2];
    const float* Wr  = (const float*)d_in[3];
    const float* Wo  = (const float*)d_in[4];
    const float* bo  = (const float*)d_in[5];
    const float* Ws1 = (const float*)d_in[6];
    const float* bs1 = (const float*)d_in[7];
    const float* Ws2 = (const float*)d_in[8];
    const float* bs2 = (const float*)d_in[9];
    const float* We1 = (const float*)d_in[10];
    const float* be1 = (const float*)d_in[11];
    const float* We2 = (const float*)d_in[12];
    const float* be2 = (const float*)d_in[13];

    float* out    = (float*)d_out;
    float* bigram = out;
    float* start  = out + (size_t)Bc * Nc * Nc;
    float* end    = start + (size_t)Bc * Nc;

    ushort_t* leftH  = (ushort_t*)d_ws;                        // 2048*128 f16
    ushort_t* rightH = leftH + (size_t)ROWS * Pc;              // 2048*128 f16
    float* parts     = (float*)(rightH + (size_t)ROWS * Pc);   // 4*2048 f32
    ushort_t* WcatT2 = (ushort_t*)(parts + 4 * ROWS);          // 512*512 bf16

    wconv_kernel<<<64, 256, 0, stream>>>(Wl, Wr, Ws1, We1, WcatT2);

    mfma_proj4<<<dim3(64, 8), 256, 0, stream>>>(
        input, WcatT2, bl, bs1, Ws2, be1, We2, leftH, rightH, parts);

    bigram_kernel<<<dim3(9, 8, 4), 256, 0, stream>>>(
        leftH, rightH, Wo, bo, parts, bs2, be2, bigram, start, end);
}

// Round 12
// 31.045 us; speedup vs baseline: 13.3144x; 1.1689x over previous
//
#include <hip/hip_runtime.h>

typedef unsigned short ushort_t;
using f32x4  = __attribute__((ext_vector_type(4))) float;
using bf16x8 = __attribute__((ext_vector_type(8))) short;
using u16x8  = __attribute__((ext_vector_type(8))) unsigned short;
using h2v    = __attribute__((ext_vector_type(2))) _Float16;
using u32x4  = __attribute__((ext_vector_type(4))) unsigned;

constexpr int Bc = 4;
constexpr int Nc = 512;
constexpr int Dc = 512;
constexpr int Pc = 128;
constexpr int ROWS = Bc * Nc;   // 2048

__device__ inline unsigned short f2bf(float f) {
    unsigned u = __builtin_bit_cast(unsigned, f);
    unsigned r = u + 0x7fffu + ((u >> 16) & 1u);   // RNE
    return (unsigned short)(r >> 16);
}

__device__ inline void gload_lds16(const void* g, void* l) {
    __builtin_amdgcn_global_load_lds(
        (const __attribute__((address_space(1))) unsigned int*)g,
        (__attribute__((address_space(3))) unsigned int*)l, 16, 0, 0);
}

__device__ inline unsigned packh2(float a, float b) {
    unsigned short lo = __builtin_bit_cast(unsigned short, (_Float16)a);
    unsigned short hi = __builtin_bit_cast(unsigned short, (_Float16)b);
    return (unsigned)lo | ((unsigned)hi << 16);
}

// ---------------------------------------------------------------------------
// K0: W-only convert -> WcatT2[nt(8)][ks(8)][kc(8)][col(64)][8] bf16.
// (round-8 version, exact)
// ---------------------------------------------------------------------------
__global__ __launch_bounds__(256) void wconv_kernel(
    const float* __restrict__ Wl,  const float* __restrict__ Wr,
    const float* __restrict__ Ws1, const float* __restrict__ We1,
    ushort_t* __restrict__ WcatT2)
{
    const int bx = blockIdx.x, t = threadIdx.x;
    __shared__ float T[64][68];

    const int nt = bx >> 3, ks = bx & 7;
    const int mi = nt >> 1, cm0 = (nt & 1) * 64;
    const float* Wm = (mi == 0) ? Wl : (mi == 1) ? Wr : (mi == 2) ? Ws1 : We1;

    const int kk_ = t >> 4, cc = (t & 15) << 2;
    #pragma unroll
    for (int u = 0; u < 4; ++u)
        *(float4*)&T[kk_ + 16 * u][cc] =
            *(const float4*)&Wm[(size_t)(ks * 64 + kk_ + 16 * u) * Pc + cm0 + cc];
    __syncthreads();

    const int col = t & 63, c2 = t >> 6;
    #pragma unroll
    for (int h = 0; h < 2; ++h) {
        const int kc = c2 + h * 4;
        u16x8 o;
        #pragma unroll
        for (int i = 0; i < 8; ++i) o[i] = f2bf(T[kc * 8 + i][col]);
        *(u16x8*)(WcatT2 + ((size_t)(nt * 8 + ks) * 8 + kc) * 512 + col * 8) = o;
    }
}

// ---------------------------------------------------------------------------
// K1: proj GEMM with fused input conversion (round-8 structure, unchanged).
// ---------------------------------------------------------------------------
__global__ __launch_bounds__(256) void mfma_proj4(
    const float* __restrict__ input, const ushort_t* __restrict__ WcatT2,
    const float* __restrict__ bl,
    const float* __restrict__ bs1, const float* __restrict__ Ws2,
    const float* __restrict__ be1, const float* __restrict__ We2,
    ushort_t* __restrict__ leftH, ushort_t* __restrict__ rightH,
    float* __restrict__ parts)
{
    const int mt2 = blockIdx.x, ny = blockIdx.y;
    const int row0 = mt2 * 32;
    const int t = threadIdx.x, w = t >> 6, l = t & 63;
    const int wm = w & 1, wn = w >> 1;
    const int fr = l & 15, fg = l >> 4;

    __shared__ ushort_t As[2][2048];
    __shared__ ushort_t Bs[2][4096];
    __shared__ float red[64];

    const ushort_t* Bbase = WcatT2 + (size_t)ny * 8 * 4096;

    const int sr = t >> 3, skc = t & 7;
    const float* Ain = input + (size_t)(row0 + sr) * Dc + skc * 8;
    ushort_t* Ad0 = &As[0][skc * 256 + sr * 8];
    ushort_t* Ad1 = &As[1][skc * 256 + sr * 8];

    f32x4 acc0 = {0.f, 0.f, 0.f, 0.f}, acc1 = {0.f, 0.f, 0.f, 0.f};
    float4 aE0, aE1, aO0, aO1;

#define ALOAD(P0, P1, KS)                                     \
    {                                                         \
        const float* s_ = Ain + (KS) * 64;                    \
        P0 = *(const float4*)s_;                              \
        P1 = *(const float4*)(s_ + 4);                        \
    }

#define AWRITE(DST, P0, P1)                                   \
    {                                                         \
        u16x8 o_;                                             \
        o_[0] = f2bf(P0.x); o_[1] = f2bf(P0.y);               \
        o_[2] = f2bf(P0.z); o_[3] = f2bf(P0.w);               \
        o_[4] = f2bf(P1.x); o_[5] = f2bf(P1.y);               \
        o_[6] = f2bf(P1.z); o_[7] = f2bf(P1.w);               \
        *(u16x8*)(DST) = o_;                                  \
    }

#define BSTAGE(BI, KS)                                                   \
    {                                                                    \
        const ushort_t* gb = Bbase + (KS) * 4096;                        \
        gload_lds16(gb + w * 512 + l * 8, &Bs[BI][w * 512]);             \
        gload_lds16(gb + (w + 4) * 512 + l * 8, &Bs[BI][(w + 4) * 512]); \
    }

#define COMPUTE(BI)                                                           \
    {                                                                         \
        _Pragma("unroll") for (int kk = 0; kk < 2; ++kk) {                    \
            const int kc = kk * 4 + fg;                                       \
            bf16x8 a  = *(const bf16x8*)&As[BI][kc * 256 + (wm * 16 + fr) * 8];       \
            bf16x8 b0 = *(const bf16x8*)&Bs[BI][kc * 512 + (wn * 32 + fr) * 8];       \
            bf16x8 b1 = *(const bf16x8*)&Bs[BI][kc * 512 + (wn * 32 + 16 + fr) * 8];  \
            acc0 = __builtin_amdgcn_mfma_f32_16x16x32_bf16(a, b0, acc0, 0, 0, 0);     \
            acc1 = __builtin_amdgcn_mfma_f32_16x16x32_bf16(a, b1, acc1, 0, 0, 0);     \
        }                                                                     \
    }

    ALOAD(aE0, aE1, 0);
    BSTAGE(0, 0);
    AWRITE(Ad0, aE0, aE1);
    ALOAD(aO0, aO1, 1);
    __syncthreads();

    #pragma unroll
    for (int ks2 = 0; ks2 < 8; ks2 += 2) {
        BSTAGE(1, ks2 + 1);
        if (ks2 + 2 < 8) ALOAD(aE0, aE1, ks2 + 2);
        COMPUTE(0);
        AWRITE(Ad1, aO0, aO1);
        __syncthreads();
        if (ks2 + 2 < 8) {
            BSTAGE(0, ks2 + 2);
            if (ks2 + 3 < 8) ALOAD(aO0, aO1, ks2 + 3);
        }
        COMPUTE(1);
        if (ks2 + 2 < 8) AWRITE(Ad0, aE0, aE1);
        __syncthreads();
    }
#undef ALOAD
#undef AWRITE
#undef BSTAGE
#undef COMPUTE

    const int fq4 = fg << 2;
    if (ny < 4) {
        ushort_t* outp = (ny < 2) ? leftH : rightH;
        const int cb = (ny & 1) * 64 + wn * 32;
        #pragma unroll
        for (int n = 0; n < 2; ++n) {
            const int col = cb + n * 16 + fr;
            const float bv = (ny < 2) ? bl[col] : 0.f;
            const f32x4 av = n ? acc1 : acc0;
            #pragma unroll
            for (int q = 0; q < 4; ++q) {
                float v = av[q] + bv;
                outp[(size_t)(row0 + wm * 16 + fq4 + q) * Pc + col] =
                    __builtin_bit_cast(ushort_t, (_Float16)v);
            }
        }
    } else {
        const int pi = ny - 4;
        const float* b1 = (ny < 6) ? bs1 : be1;
        const float* W2 = (ny < 6) ? Ws2 : We2;
        const int pb = (pi & 1) * 64;
        #pragma unroll
        for (int q = 0; q < 4; ++q) {
            const int cp0 = pb + wn * 32 + fr;
            const int cp1 = pb + wn * 32 + 16 + fr;
            float v = fmaxf(acc0[q] + b1[cp0], 0.f) * W2[cp0]
                    + fmaxf(acc1[q] + b1[cp1], 0.f) * W2[cp1];
            v += __shfl_xor(v, 1);
            v += __shfl_xor(v, 2);
            v += __shfl_xor(v, 4);
            v += __shfl_xor(v, 8);
            if (fr == 0) red[wn * 32 + wm * 16 + fq4 + q] = v;
        }
        __syncthreads();
        if (t < 32) parts[pi * ROWS + row0 + t] = red[t] + red[32 + t];
    }
}

// ---------------------------------------------------------------------------
// K2: bigram v8 — register/broadcast engine, clean-room rewrite.
// Block: 256 thr (4 waves). lane owns j = jt*64 + lane (L column in VGPRs);
// wave w owns i-rows it*32 + w*8 + 0..7 (R rows via broadcast u32x4 reads);
// Wo packed to f16 pairs in-kernel (v5-proven path). p in 2 halves of 64.
// grid (9, 16, 4): jt==8 (it<8) combines start/end partials.
// ---------------------------------------------------------------------------
__global__ __launch_bounds__(256) void bigram_kernel(
    const ushort_t* __restrict__ leftH, const ushort_t* __restrict__ rightH,
    const float* __restrict__ Wo,   const float* __restrict__ bo,
    const float* __restrict__ parts,
    const float* __restrict__ bs2,  const float* __restrict__ be2,
    float* __restrict__ out, float* __restrict__ start_out,
    float* __restrict__ end_out)
{
    const int jt = blockIdx.x, it = blockIdx.y, b = blockIdx.z;
    const int t  = threadIdx.x;

    if (jt == 8) {
        if (it < 8) {
            const int base = (b * 8 + it) * 64;
            if (t < 64) {
                const int r = base + t;
                start_out[r] = parts[r] + parts[ROWS + r] + bs2[0];
            } else if (t < 128) {
                const int r = base + t - 64;
                end_out[r] = parts[2 * ROWS + r] + parts[3 * ROWS + r] + be2[0];
            }
        }
        return;
    }

    __shared__ unsigned Lh[64 * 68];   // 64 j-rows, 64 pairs + pad
    __shared__ unsigned Rh[32 * 68];   // 32 i-rows
    __shared__ unsigned woS[64];

    const int lane = t & 63, w = t >> 6;

    if (t < 64) woS[t] = packh2(Wo[2 * t], Wo[2 * t + 1]);

    // stage L: 64 rows x 16 chunks of 16B (v4-proven pattern, stride 68)
    const ushort_t* lbase = leftH + ((size_t)b * Nc + jt * 64) * Pc;
    #pragma unroll
    for (int u = 0; u < 4; ++u) {
        int idx = t + u * 256, row = idx >> 4, c4 = idx & 15;
        *(u32x4*)&Lh[row * 68 + c4 * 4] =
            *(const u32x4*)(lbase + (size_t)row * Pc + c4 * 8);
    }
    // stage R: 32 rows x 16 chunks
    const ushort_t* rbase = rightH + ((size_t)b * Nc + it * 32) * Pc;
    #pragma unroll
    for (int u = 0; u < 2; ++u) {
        int idx = t + u * 256, row = idx >> 4, c4 = idx & 15;
        *(u32x4*)&Rh[row * 68 + c4 * 4] =
            *(const u32x4*)(rbase + (size_t)row * Pc + c4 * 8);
    }
    __syncthreads();

    float acc0[8] = {}, acc1[8] = {};
    const h2v hz = {(_Float16)0.f, (_Float16)0.f};
    const unsigned* lrow = &Lh[lane * 68];      // this lane's j-column
    const unsigned* rw   = &Rh[(w * 8) * 68];   // this wave's 8 i-rows

    #pragma unroll
    for (int half = 0; half < 2; ++half) {
        const int hoff = half * 32;

        unsigned lreg[32];
        #pragma unroll
        for (int c = 0; c < 8; ++c) {
            u32x4 v = *(const u32x4*)&lrow[hoff + 4 * c];
            lreg[4 * c]     = v[0]; lreg[4 * c + 1] = v[1];
            lreg[4 * c + 2] = v[2]; lreg[4 * c + 3] = v[3];
        }
        unsigned wreg[32];
        #pragma unroll
        for (int c = 0; c < 8; ++c) {
            u32x4 v = *(const u32x4*)&woS[hoff + 4 * c];
            wreg[4 * c]     = v[0]; wreg[4 * c + 1] = v[1];
            wreg[4 * c + 2] = v[2]; wreg[4 * c + 3] = v[3];
        }

        #pragma unroll
        for (int i = 0; i < 8; ++i) {
            unsigned rreg[32];
            #pragma unroll
            for (int c = 0; c < 8; ++c) {
                u32x4 v = *(const u32x4*)&rw[i * 68 + hoff + 4 * c];
                rreg[4 * c]     = v[0]; rreg[4 * c + 1] = v[1];
                rreg[4 * c + 2] = v[2]; rreg[4 * c + 3] = v[3];
            }
            float a0 = acc0[i], a1 = acc1[i];
            #pragma unroll
            for (int m = 0; m < 32; m += 2) {
                h2v s0 = __builtin_bit_cast(h2v, lreg[m])
                       + __builtin_bit_cast(h2v, rreg[m]);
                s0 = __builtin_elementwise_max(s0, hz);
                a0 = __builtin_amdgcn_fdot2(
                         s0, __builtin_bit_cast(h2v, wreg[m]), a0, false);
                h2v s1 = __builtin_bit_cast(h2v, lreg[m + 1])
                       + __builtin_bit_cast(h2v, rreg[m + 1]);
                s1 = __builtin_elementwise_max(s1, hz);
                a1 = __builtin_amdgcn_fdot2(
                         s1, __builtin_bit_cast(h2v, wreg[m + 1]), a1, false);
            }
            acc0[i] = a0; acc1[i] = a1;
        }
    }

    const float bias = bo[0];
    const int gi0 = it * 32 + w * 8;
    const int gj  = jt * 64 + lane;
    #pragma unroll
    for (int i = 0; i < 8; ++i)
        out[((size_t)b * Nc + gi0 + i) * Nc + gj] = acc0[i] + acc1[i] + bias;
}

extern "C" void kernel_launch(void* const* d_in, const int* in_sizes, int n_in,
                              void* d_out, int out_size, void* d_ws, size_t ws_size,
                              hipStream_t stream) {
    const float* input = (const float*)d_in[0];
    const float* Wl  = (const float*)d_in[1];
    const float* bl  = (const float*)d_in[2];
    const float* Wr  = (const float*)d_in[3];
    const float* Wo  = (const float*)d_in[4];
    const float* bo  = (const float*)d_in[5];
    const float* Ws1 = (const float*)d_in[6];
    const float* bs1 = (const float*)d_in[7];
    const float* Ws2 = (const float*)d_in[8];
    const float* bs2 = (const float*)d_in[9];
    const float* We1 = (const float*)d_in[10];
    const float* be1 = (const float*)d_in[11];
    const float* We2 = (const float*)d_in[12];
    const float* be2 = (const float*)d_in[13];

    float* out    = (float*)d_out;
    float* bigram = out;
    float* start  = out + (size_t)Bc * Nc * Nc;
    float* end    = start + (size_t)Bc * Nc;

    ushort_t* leftH  = (ushort_t*)d_ws;                        // 2048*128 f16
    ushort_t* rightH = leftH + (size_t)ROWS * Pc;              // 2048*128 f16
    float* parts     = (float*)(rightH + (size_t)ROWS * Pc);   // 4*2048 f32
    ushort_t* WcatT2 = (ushort_t*)(parts + 4 * ROWS);          // 512*512 bf16

    wconv_kernel<<<64, 256, 0, stream>>>(Wl, Wr, Ws1, We1, WcatT2);

    mfma_proj4<<<dim3(64, 8), 256, 0, stream>>>(
        input, WcatT2, bl, bs1, Ws2, be1, We2, leftH, rightH, parts);

    bigram_kernel<<<dim3(9, 16, 4), 256, 0, stream>>>(
        leftH, rightH, Wo, bo, parts, bs2, be2, bigram, start, end);
}

// Round 13
// 30.851 us; speedup vs baseline: 13.3979x; 1.0063x over previous
//
#include <hip/hip_runtime.h>

typedef unsigned short ushort_t;
using f32x4  = __attribute__((ext_vector_type(4))) float;
using bf16x8 = __attribute__((ext_vector_type(8))) short;
using u16x8  = __attribute__((ext_vector_type(8))) unsigned short;
using h2v    = __attribute__((ext_vector_type(2))) _Float16;
using u32x4  = __attribute__((ext_vector_type(4))) unsigned;

constexpr int Bc = 4;
constexpr int Nc = 512;
constexpr int Dc = 512;
constexpr int Pc = 128;
constexpr int ROWS = Bc * Nc;   // 2048

__device__ inline unsigned short f2bf(float f) {
    unsigned u = __builtin_bit_cast(unsigned, f);
    unsigned r = u + 0x7fffu + ((u >> 16) & 1u);   // RNE
    return (unsigned short)(r >> 16);
}

__device__ inline void gload_lds16(const void* g, void* l) {
    __builtin_amdgcn_global_load_lds(
        (const __attribute__((address_space(1))) unsigned int*)g,
        (__attribute__((address_space(3))) unsigned int*)l, 16, 0, 0);
}

__device__ inline unsigned packh2(float a, float b) {
    unsigned short lo = __builtin_bit_cast(unsigned short, (_Float16)a);
    unsigned short hi = __builtin_bit_cast(unsigned short, (_Float16)b);
    return (unsigned)lo | ((unsigned)hi << 16);
}

// ---------------------------------------------------------------------------
// K0: W-only convert -> WcatT2[nt(8)][ks(8)][kc(8)][col(64)][8] bf16.
// (round-8 version, exact — unchanged)
// ---------------------------------------------------------------------------
__global__ __launch_bounds__(256) void wconv_kernel(
    const float* __restrict__ Wl,  const float* __restrict__ Wr,
    const float* __restrict__ Ws1, const float* __restrict__ We1,
    ushort_t* __restrict__ WcatT2)
{
    const int bx = blockIdx.x, t = threadIdx.x;
    __shared__ float T[64][68];

    const int nt = bx >> 3, ks = bx & 7;
    const int mi = nt >> 1, cm0 = (nt & 1) * 64;
    const float* Wm = (mi == 0) ? Wl : (mi == 1) ? Wr : (mi == 2) ? Ws1 : We1;

    const int kk_ = t >> 4, cc = (t & 15) << 2;
    #pragma unroll
    for (int u = 0; u < 4; ++u)
        *(float4*)&T[kk_ + 16 * u][cc] =
            *(const float4*)&Wm[(size_t)(ks * 64 + kk_ + 16 * u) * Pc + cm0 + cc];
    __syncthreads();

    const int col = t & 63, c2 = t >> 6;
    #pragma unroll
    for (int h = 0; h < 2; ++h) {
        const int kc = c2 + h * 4;
        u16x8 o;
        #pragma unroll
        for (int i = 0; i < 8; ++i) o[i] = f2bf(T[kc * 8 + i][col]);
        *(u16x8*)(WcatT2 + ((size_t)(nt * 8 + ks) * 8 + kc) * 512 + col * 8) = o;
    }
}

// ---------------------------------------------------------------------------
// K1: proj GEMM with fused input conversion (round-8 structure, unchanged).
// ---------------------------------------------------------------------------
__global__ __launch_bounds__(256) void mfma_proj4(
    const float* __restrict__ input, const ushort_t* __restrict__ WcatT2,
    const float* __restrict__ bl,
    const float* __restrict__ bs1, const float* __restrict__ Ws2,
    const float* __restrict__ be1, const float* __restrict__ We2,
    ushort_t* __restrict__ leftH, ushort_t* __restrict__ rightH,
    float* __restrict__ parts)
{
    const int mt2 = blockIdx.x, ny = blockIdx.y;
    const int row0 = mt2 * 32;
    const int t = threadIdx.x, w = t >> 6, l = t & 63;
    const int wm = w & 1, wn = w >> 1;
    const int fr = l & 15, fg = l >> 4;

    __shared__ ushort_t As[2][2048];
    __shared__ ushort_t Bs[2][4096];
    __shared__ float red[64];

    const ushort_t* Bbase = WcatT2 + (size_t)ny * 8 * 4096;

    const int sr = t >> 3, skc = t & 7;
    const float* Ain = input + (size_t)(row0 + sr) * Dc + skc * 8;
    ushort_t* Ad0 = &As[0][skc * 256 + sr * 8];
    ushort_t* Ad1 = &As[1][skc * 256 + sr * 8];

    f32x4 acc0 = {0.f, 0.f, 0.f, 0.f}, acc1 = {0.f, 0.f, 0.f, 0.f};
    float4 aE0, aE1, aO0, aO1;

#define ALOAD(P0, P1, KS)                                     \
    {                                                         \
        const float* s_ = Ain + (KS) * 64;                    \
        P0 = *(const float4*)s_;                              \
        P1 = *(const float4*)(s_ + 4);                        \
    }

#define AWRITE(DST, P0, P1)                                   \
    {                                                         \
        u16x8 o_;                                             \
        o_[0] = f2bf(P0.x); o_[1] = f2bf(P0.y);               \
        o_[2] = f2bf(P0.z); o_[3] = f2bf(P0.w);               \
        o_[4] = f2bf(P1.x); o_[5] = f2bf(P1.y);               \
        o_[6] = f2bf(P1.z); o_[7] = f2bf(P1.w);               \
        *(u16x8*)(DST) = o_;                                  \
    }

#define BSTAGE(BI, KS)                                                   \
    {                                                                    \
        const ushort_t* gb = Bbase + (KS) * 4096;                        \
        gload_lds16(gb + w * 512 + l * 8, &Bs[BI][w * 512]);             \
        gload_lds16(gb + (w + 4) * 512 + l * 8, &Bs[BI][(w + 4) * 512]); \
    }

#define COMPUTE(BI)                                                           \
    {                                                                         \
        _Pragma("unroll") for (int kk = 0; kk < 2; ++kk) {                    \
            const int kc = kk * 4 + fg;                                       \
            bf16x8 a  = *(const bf16x8*)&As[BI][kc * 256 + (wm * 16 + fr) * 8];       \
            bf16x8 b0 = *(const bf16x8*)&Bs[BI][kc * 512 + (wn * 32 + fr) * 8];       \
            bf16x8 b1 = *(const bf16x8*)&Bs[BI][kc * 512 + (wn * 32 + 16 + fr) * 8];  \
            acc0 = __builtin_amdgcn_mfma_f32_16x16x32_bf16(a, b0, acc0, 0, 0, 0);     \
            acc1 = __builtin_amdgcn_mfma_f32_16x16x32_bf16(a, b1, acc1, 0, 0, 0);     \
        }                                                                     \
    }

    ALOAD(aE0, aE1, 0);
    BSTAGE(0, 0);
    AWRITE(Ad0, aE0, aE1);
    ALOAD(aO0, aO1, 1);
    __syncthreads();

    #pragma unroll
    for (int ks2 = 0; ks2 < 8; ks2 += 2) {
        BSTAGE(1, ks2 + 1);
        if (ks2 + 2 < 8) ALOAD(aE0, aE1, ks2 + 2);
        COMPUTE(0);
        AWRITE(Ad1, aO0, aO1);
        __syncthreads();
        if (ks2 + 2 < 8) {
            BSTAGE(0, ks2 + 2);
            if (ks2 + 3 < 8) ALOAD(aO0, aO1, ks2 + 3);
        }
        COMPUTE(1);
        if (ks2 + 2 < 8) AWRITE(Ad0, aE0, aE1);
        __syncthreads();
    }
#undef ALOAD
#undef AWRITE
#undef BSTAGE
#undef COMPUTE

    const int fq4 = fg << 2;
    if (ny < 4) {
        ushort_t* outp = (ny < 2) ? leftH : rightH;
        const int cb = (ny & 1) * 64 + wn * 32;
        #pragma unroll
        for (int n = 0; n < 2; ++n) {
            const int col = cb + n * 16 + fr;
            const float bv = (ny < 2) ? bl[col] : 0.f;
            const f32x4 av = n ? acc1 : acc0;
            #pragma unroll
            for (int q = 0; q < 4; ++q) {
                float v = av[q] + bv;
                outp[(size_t)(row0 + wm * 16 + fq4 + q) * Pc + col] =
                    __builtin_bit_cast(ushort_t, (_Float16)v);
            }
        }
    } else {
        const int pi = ny - 4;
        const float* b1 = (ny < 6) ? bs1 : be1;
        const float* W2 = (ny < 6) ? Ws2 : We2;
        const int pb = (pi & 1) * 64;
        #pragma unroll
        for (int q = 0; q < 4; ++q) {
            const int cp0 = pb + wn * 32 + fr;
            const int cp1 = pb + wn * 32 + 16 + fr;
            float v = fmaxf(acc0[q] + b1[cp0], 0.f) * W2[cp0]
                    + fmaxf(acc1[q] + b1[cp1], 0.f) * W2[cp1];
            v += __shfl_xor(v, 1);
            v += __shfl_xor(v, 2);
            v += __shfl_xor(v, 4);
            v += __shfl_xor(v, 8);
            if (fr == 0) red[wn * 32 + wm * 16 + fq4 + q] = v;
        }
        __syncthreads();
        if (t < 32) parts[pi * ROWS + row0 + t] = red[t] + red[32 + t];
    }
}

// ---------------------------------------------------------------------------
// K2: bigram v9 — no-LDS, no-barrier, 1-wave blocks for latency tolerance.
// grid (128, 9, 4), block 64. y<8: compute; lane owns j = y*64 + lane
// (L column in VGPRs, read direct from global); block owns 4 i-rows
// i0 = x*4 (R rows + Wo are blockIdx-uniform -> scalarizable loads).
// p in 2 halves of 64. Same fdot2 arithmetic as v8 (proven correct).
// y==8 (x<8): combine start/end partials.
// ---------------------------------------------------------------------------
__global__ __launch_bounds__(64, 4) void bigram_kernel(
    const ushort_t* __restrict__ leftH, const ushort_t* __restrict__ rightH,
    const float* __restrict__ Wo,   const float* __restrict__ bo,
    const float* __restrict__ parts,
    const float* __restrict__ bs2,  const float* __restrict__ be2,
    float* __restrict__ out, float* __restrict__ start_out,
    float* __restrict__ end_out)
{
    const int x = blockIdx.x, y = blockIdx.y, b = blockIdx.z;
    const int t = threadIdx.x;

    if (y == 8) {
        if (x < 8) {
            const int r = (b * 8 + x) * 64 + t;
            start_out[r] = parts[r] + parts[ROWS + r] + bs2[0];
            end_out[r]   = parts[2 * ROWS + r] + parts[3 * ROWS + r] + be2[0];
        }
        return;
    }

    const int j  = y * 64 + t;
    const int i0 = x * 4;

    const ushort_t* lrow  = leftH  + ((size_t)b * Nc + j) * Pc;    // per-lane
    const ushort_t* rbase = rightH + ((size_t)b * Nc + i0) * Pc;   // uniform

    float acc0[4] = {}, acc1[4] = {};
    const h2v hz = {(_Float16)0.f, (_Float16)0.f};

    #pragma unroll
    for (int half = 0; half < 2; ++half) {
        const int hoff = half * 64;   // ushort offset

        // L: this lane's j-column half (128 B), direct from global.
        unsigned lreg[32];
        #pragma unroll
        for (int c = 0; c < 8; ++c) {
            u32x4 v = *(const u32x4*)(lrow + hoff + c * 8);
            lreg[4 * c]     = v[0]; lreg[4 * c + 1] = v[1];
            lreg[4 * c + 2] = v[2]; lreg[4 * c + 3] = v[3];
        }
        // Wo: uniform fp32 -> packed f16 pairs.
        unsigned wreg[32];
        #pragma unroll
        for (int m = 0; m < 32; ++m)
            wreg[m] = packh2(Wo[hoff + 2 * m], Wo[hoff + 2 * m + 1]);

        #pragma unroll
        for (int i = 0; i < 4; ++i) {
            // R row i half: uniform address -> broadcast/scalar loads.
            unsigned rreg[32];
            #pragma unroll
            for (int c = 0; c < 8; ++c) {
                u32x4 v = *(const u32x4*)(rbase + (size_t)i * Pc + hoff + c * 8);
                rreg[4 * c]     = v[0]; rreg[4 * c + 1] = v[1];
                rreg[4 * c + 2] = v[2]; rreg[4 * c + 3] = v[3];
            }
            float a0 = acc0[i], a1 = acc1[i];
            #pragma unroll
            for (int m = 0; m < 32; m += 2) {
                h2v s0 = __builtin_bit_cast(h2v, lreg[m])
                       + __builtin_bit_cast(h2v, rreg[m]);
                s0 = __builtin_elementwise_max(s0, hz);
                a0 = __builtin_amdgcn_fdot2(
                         s0, __builtin_bit_cast(h2v, wreg[m]), a0, false);
                h2v s1 = __builtin_bit_cast(h2v, lreg[m + 1])
                       + __builtin_bit_cast(h2v, rreg[m + 1]);
                s1 = __builtin_elementwise_max(s1, hz);
                a1 = __builtin_amdgcn_fdot2(
                         s1, __builtin_bit_cast(h2v, wreg[m + 1]), a1, false);
            }
            acc0[i] = a0; acc1[i] = a1;
        }
    }

    const float bias = bo[0];
    #pragma unroll
    for (int i = 0; i < 4; ++i)
        out[((size_t)b * Nc + i0 + i) * Nc + j] = acc0[i] + acc1[i] + bias;
}

extern "C" void kernel_launch(void* const* d_in, const int* in_sizes, int n_in,
                              void* d_out, int out_size, void* d_ws, size_t ws_size,
                              hipStream_t stream) {
    const float* input = (const float*)d_in[0];
    const float* Wl  = (const float*)d_in[1];
    const float* bl  = (const float*)d_in[2];
    const float* Wr  = (const float*)d_in[3];
    const float* Wo  = (const float*)d_in[4];
    const float* bo  = (const float*)d_in[5];
    const float* Ws1 = (const float*)d_in[6];
    const float* bs1 = (const float*)d_in[7];
    const float* Ws2 = (const float*)d_in[8];
    const float* bs2 = (const float*)d_in[9];
    const float* We1 = (const float*)d_in[10];
    const float* be1 = (const float*)d_in[11];
    const float* We2 = (const float*)d_in[12];
    const float* be2 = (const float*)d_in[13];

    float* out    = (float*)d_out;
    float* bigram = out;
    float* start  = out + (size_t)Bc * Nc * Nc;
    float* end    = start + (size_t)Bc * Nc;

    ushort_t* leftH  = (ushort_t*)d_ws;                        // 2048*128 f16
    ushort_t* rightH = leftH + (size_t)ROWS * Pc;              // 2048*128 f16
    float* parts     = (float*)(rightH + (size_t)ROWS * Pc);   // 4*2048 f32
    ushort_t* WcatT2 = (ushort_t*)(parts + 4 * ROWS);          // 512*512 bf16

    wconv_kernel<<<64, 256, 0, stream>>>(Wl, Wr, Ws1, We1, WcatT2);

    mfma_proj4<<<dim3(64, 8), 256, 0, stream>>>(
        input, WcatT2, bl, bs1, Ws2, be1, We2, leftH, rightH, parts);

    bigram_kernel<<<dim3(128, 9, 4), 64, 0, stream>>>(
        leftH, rightH, Wo, bo, parts, bs2, be2, bigram, start, end);
}